// Round 1
// baseline (240.134 us; speedup 1.0000x reference)
//
#include <hip/hip_runtime.h>

// Problem constants (match reference)
#define BB 4096
#define DD 8192
#define KK 5
#define GS 40
#define MAXIT 3
#define EFF 17            // 4*(KK-1)+1 composed taps
#define D4 (DD/4)         // float4 elements per row = 2048

// ---------------------------------------------------------------------------
// Kernel 1: max_it = max(|g|) / GS over the batch  -> ws[0]
// ---------------------------------------------------------------------------
__global__ __launch_bounds__(256) void k_max_it(const int* __restrict__ g,
                                                int* __restrict__ ws) {
    __shared__ int red[256];
    int t = threadIdx.x;
    int m = 0;
    for (int i = t; i < BB; i += 256) {
        int a = g[i];
        a = a < 0 ? -a : a;
        m = max(m, a / GS);
    }
    red[t] = m;
    __syncthreads();
    for (int s = 128; s > 0; s >>= 1) {
        if (t < s) red[t] = max(red[t], red[t + s]);
        __syncthreads();
    }
    if (t == 0) ws[0] = red[0];
}

// ---------------------------------------------------------------------------
// Kernel 2: one block per row. Stage row to LDS, compose the effective 17-tap
// circular kernel per row (redundant per thread; ~400 FLOPs, hides staging
// latency), then out[d] = sum_m E[m] * x[(d+m-8) mod D].
// ---------------------------------------------------------------------------
__global__ __launch_bounds__(256) void k_conv(const float* __restrict__ x,
                                              const int* __restrict__ g,
                                              const float* __restrict__ kernels,
                                              const int* __restrict__ ws,
                                              float* __restrict__ out) {
    __shared__ float row[DD];          // 32 KB
    const int b = blockIdx.x;
    const int t = threadIdx.x;

    // --- stage row: coalesced float4 loads, 8 per thread ---
    const float4* xr = (const float4*)(x + (size_t)b * DD);
    float4* rowv = (float4*)row;
#pragma unroll
    for (int i = 0; i < D4 / 256; ++i)
        rowv[i * 256 + t] = xr[i * 256 + t];

    // --- compose effective kernel (overlaps staging latency) ---
    const int gv = g[b];
    const int sign = gv > 0 ? 1 : (gv < 0 ? -1 : 0);
    const int a = gv < 0 ? -gv : gv;
    const int iters = a / GS;
    const int rem = a % GS;
    const int max_it = ws[0];

    float maxk[KK], idk[KK], fink[KK];
    const float* mk = kernels + (size_t)(sign * GS + GS) * KK;
    const float* ik = kernels + (size_t)GS * KK;
    const float* fk = kernels + (size_t)(rem * sign + GS) * KK;
#pragma unroll
    for (int j = 0; j < KK; ++j) { maxk[j] = mk[j]; idk[j] = ik[j]; fink[j] = fk[j]; }

    float e[EFF], ne[EFF];
#pragma unroll
    for (int m = 0; m < EFF; ++m) e[m] = 0.f;
    e[0] = 1.f;
    int len = 1;
    for (int i = 0; i < MAXIT; ++i) {
        float kk5[KK];
        if (i < iters) {
#pragma unroll
            for (int j = 0; j < KK; ++j) kk5[j] = maxk[j];
        } else if (i < max_it) {
#pragma unroll
            for (int j = 0; j < KK; ++j) kk5[j] = idk[j];
        } else {
#pragma unroll
            for (int j = 0; j < KK; ++j) kk5[j] = (j == (KK - 1) / 2) ? 1.f : 0.f;
        }
#pragma unroll
        for (int m = 0; m < EFF; ++m) ne[m] = 0.f;
        for (int m = 0; m < len; ++m)
#pragma unroll
            for (int j = 0; j < KK; ++j) ne[m + j] += e[m] * kk5[j];
        len += KK - 1;
#pragma unroll
        for (int m = 0; m < EFF; ++m) e[m] = ne[m];
    }
    // final kernel
#pragma unroll
    for (int m = 0; m < EFF; ++m) ne[m] = 0.f;
    for (int m = 0; m < len; ++m)
#pragma unroll
        for (int j = 0; j < KK; ++j) ne[m + j] += e[m] * fink[j];
#pragma unroll
    for (int m = 0; m < EFF; ++m) e[m] = ne[m];

    __syncthreads();

    // --- compute: 8 float4 outputs per thread, strided for coalescing ---
    float4* outr = (float4*)(out + (size_t)b * DD);
#pragma unroll
    for (int jb = 0; jb < D4 / 256; ++jb) {
        const int v = jb * 256 + t;          // output float4 index; d0 = 4*v
        float f[EFF + 3];                    // inputs x[d0-8 .. d0+11]
#pragma unroll
        for (int q = 0; q < 5; ++q) {
            unsigned idx = (unsigned)(v - 2 + q) & (D4 - 1);   // circular wrap
            float4 val = rowv[idx];
            f[q * 4 + 0] = val.x; f[q * 4 + 1] = val.y;
            f[q * 4 + 2] = val.z; f[q * 4 + 3] = val.w;
        }
        float oc[4];
#pragma unroll
        for (int c = 0; c < 4; ++c) {
            float s = 0.f;
#pragma unroll
            for (int m = 0; m < EFF; ++m) s += e[m] * f[c + m];
            oc[c] = s;
        }
        float4 o; o.x = oc[0]; o.y = oc[1]; o.z = oc[2]; o.w = oc[3];
        outr[v] = o;
    }
}

// ---------------------------------------------------------------------------
extern "C" void kernel_launch(void* const* d_in, const int* in_sizes, int n_in,
                              void* d_out, int out_size, void* d_ws, size_t ws_size,
                              hipStream_t stream) {
    const float* x       = (const float*)d_in[0];
    const int*   g       = (const int*)d_in[1];
    const float* kernels = (const float*)d_in[2];
    float*       out     = (float*)d_out;
    int*         ws      = (int*)d_ws;

    k_max_it<<<1, 256, 0, stream>>>(g, ws);
    k_conv<<<BB, 256, 0, stream>>>(x, g, kernels, ws, out);
}